// Round 9
// baseline (71.340 us; speedup 1.0000x reference)
//
#include <hip/hip_runtime.h>
#include <hip/hip_bf16.h>
#include <float.h>
#include <limits.h>

#define FEAT    256
#define GAMMA_F 0.1f
#define EPS_F   1e-8f
#define KSEL    64        // BUDGET
#define NBUCK   4096      // 12-bit histogram of flipped-float keys
#define KSHIFT  20        // key >> KSHIFT -> bucket
#define CPW     8         // candidates per wave (8 KB of gathers in flight)
#define NB2     64        // select blocks
#define BCAP    128       // per-block survivor region (expected ~70 used)
#define FCAP    2048      // LDS fallback capacity

// Monotonic float -> uint transform (ascending order preserved).
__device__ __forceinline__ unsigned key_of(float v) {
    unsigned u = __float_as_uint(v);
    return u ^ ((u >> 31) ? 0xFFFFFFFFu : 0x80000000u);
}

__device__ __forceinline__ bool comes_first(float va, int ia, float vb, int ib) {
    return (va > vb) || (va == vb && ia < ib);
}

// ---------------------------------------------------------------------------
// Kernel 1: edge scores. One-shot waves, CPW=8: 8 independent 1 KB row
// gathers in flight per wave (2x the MLP of round-6's CPW=4), ||inj|| reduced
// once, 16 butterfly chains, lane 0 stores scores as two float4. Also zeroes
// the 2 ticket words for K2. No contended atomics (R3/R7 lesson), no
// persistent loop (one resident generation: 6250 waves < ~6k-8k capacity).
// ---------------------------------------------------------------------------
__global__ __launch_bounds__(256) void edge_score_kernel(
    const float* __restrict__ infl,
    const float* __restrict__ feats,
    const int*   __restrict__ cand,
    const float* __restrict__ inj,
    float*       __restrict__ scores,   // d_out + KSEL
    unsigned*    __restrict__ zero2,    // done/oflow ticket words
    int num_cand)
{
    const int gtid = blockIdx.x * blockDim.x + threadIdx.x;
    if (gtid < 2) zero2[gtid] = 0u;

    const int lane = threadIdx.x & 63;
    const int wid  = gtid >> 6;
    const int base = wid * CPW;
    if (base >= num_cand) return;
    const int n_here = num_cand - base;   // >= 1

    const float4 g = *reinterpret_cast<const float4*>(inj + lane * 4);
    float ng = g.x * g.x + g.y * g.y + g.z * g.z + g.w * g.w;
    #pragma unroll
    for (int off = 32; off > 0; off >>= 1) ng += __shfl_xor(ng, off);
    const float inj_n = fmaxf(sqrtf(ng), EPS_F);

    float4 f[CPW];
    #pragma unroll
    for (int k = 0; k < CPW; ++k) {
        const int idx = base + ((k < n_here) ? k : 0);
        const int row = cand[idx];     // wave-uniform -> SGPR
        f[k] = *reinterpret_cast<const float4*>(feats + (size_t)row * FEAT + lane * 4);
    }

    float dot[CPW], nf[CPW];
    #pragma unroll
    for (int k = 0; k < CPW; ++k) {
        dot[k] = f[k].x * g.x + f[k].y * g.y + f[k].z * g.z + f[k].w * g.w;
        nf[k]  = f[k].x * f[k].x + f[k].y * f[k].y + f[k].z * f[k].z + f[k].w * f[k].w;
    }
    #pragma unroll
    for (int off = 32; off > 0; off >>= 1) {
        #pragma unroll
        for (int k = 0; k < CPW; ++k) {
            dot[k] += __shfl_xor(dot[k], off);
            nf[k]  += __shfl_xor(nf[k],  off);
        }
    }

    if (lane == 0) {
        if (n_here >= CPW) {
            const float4 i0 = *reinterpret_cast<const float4*>(infl + base);
            const float4 i1 = *reinterpret_cast<const float4*>(infl + base + 4);
            const float iv[8] = {i0.x, i0.y, i0.z, i0.w, i1.x, i1.y, i1.z, i1.w};
            float s[8];
            #pragma unroll
            for (int k = 0; k < 8; ++k)
                s[k] = iv[k] - GAMMA_F * (dot[k] / (fmaxf(sqrtf(nf[k]), EPS_F) * inj_n));
            *reinterpret_cast<float4*>(scores + base)     = make_float4(s[0], s[1], s[2], s[3]);
            *reinterpret_cast<float4*>(scores + base + 4) = make_float4(s[4], s[5], s[6], s[7]);
        } else {
            #pragma unroll
            for (int k = 0; k < CPW; ++k) {   // static indexing (scratch rule)
                if (k < n_here)
                    scores[base + k] = infl[base + k]
                        - GAMMA_F * (dot[k] / (fmaxf(sqrtf(nf[k]), EPS_F) * inj_n));
            }
        }
    }
}

// ---------------------------------------------------------------------------
// Kernel 2: full selection in one launch, 64 blocks. Block b:
//   1. LDS hist of its ~782-score slice; local suffix-scan -> local bucket
//      threshold B_b (>=64 slice elements in buckets >= B_b). Correctness:
//      any global top-64 element inside slice b is within slice b's local
//      top-64, so local filtering never drops it.
//   2. Compact slice survivors (~70) into a private global region (plain
//      stores, no contended atomics), publish count.
//   3. Last-finished block (ticket): assemble ~4.3K survivors' values from
//      L2, hist THEM, global threshold, compact to ~90, bitonic-256, write
//      top-64 node indices. All phases grid-parallel except the tiny tail.
// Tie-pathology fallbacks (never expected): LDS serial-argmax (m<=FCAP),
// else 64x global argmax over the full score array.
// ---------------------------------------------------------------------------
__global__ __launch_bounds__(256) void select_kernel(
    const float* __restrict__ scores,
    unsigned*    __restrict__ counts,      // [NB2]
    unsigned*    __restrict__ ticket,      // [0]=done, [1]=oflow
    float*       __restrict__ ws_v,        // [NB2*BCAP]
    int*         __restrict__ ws_i,        // [NB2*BCAP]
    const int*   __restrict__ cand,
    float*       __restrict__ out,         // d_out[0..KSEL)
    int n)
{
    __shared__ unsigned h[NBUCK];
    __shared__ unsigned csum[256];
    __shared__ unsigned sB, sCnt;
    __shared__ int      sLast;
    __shared__ unsigned soff[NB2 + 1];
    __shared__ float    sv[FCAP];
    __shared__ int      si[FCAP];
    __shared__ float    wv[4];
    __shared__ int      wbi[4];

    const int t   = threadIdx.x;
    const int bid = blockIdx.x;
    const int SL  = (n + NB2 - 1) / NB2;
    const int lo  = bid * SL;
    const int hi  = min(n, lo + SL);
    const int cnt_here = max(hi - lo, 0);

    // --- 1. local histogram + local threshold ---
    for (int i = t; i < NBUCK; i += 256) h[i] = 0;
    __syncthreads();
    for (int i = lo + t; i < hi; i += 256)
        atomicAdd(&h[key_of(scores[i]) >> KSHIFT], 1u);
    __syncthreads();
    {
        const int hb = NBUCK - 16 * t;     // chunk t = buckets [hb-16, hb)
        unsigned s = 0;
        for (int b = hb - 16; b < hb; ++b) s += h[b];
        csum[t] = s;
    }
    __syncthreads();
    if (t == 0) {
        const unsigned need = (unsigned)min(KSEL, cnt_here);
        unsigned cum = 0;
        int tc = 0;
        for (; tc < 256; ++tc) {
            if (cum + csum[tc] >= need) break;
            cum += csum[tc];
        }
        unsigned B = 0;
        if (tc < 256) {
            int b = NBUCK - 16 * tc - 1;
            for (int k = 0; k < 16; ++k, --b) {
                cum += h[b];
                if (cum >= need) { B = (unsigned)b; break; }
            }
        }
        sB = B;
        sCnt = 0;
    }
    __syncthreads();
    const unsigned B = sB;

    // --- 2. compact slice survivors into private region ---
    for (int i = lo + t; i < hi; i += 256) {
        const float v = scores[i];
        if ((key_of(v) >> KSHIFT) >= B) {
            const unsigned p = atomicAdd(&sCnt, 1u);   // LDS atomic
            if (p < BCAP) { ws_v[bid * BCAP + p] = v; ws_i[bid * BCAP + p] = i; }
        }
    }
    __syncthreads();
    if (t == 0) {
        counts[bid] = min(sCnt, (unsigned)BCAP);
        if (sCnt > BCAP) atomicAdd(&ticket[1], 1u);    // never expected
    }

    // --- ticket: last-finished block runs the tail ---
    __threadfence();
    __syncthreads();
    if (t == 0) sLast = (atomicAdd(&ticket[0], 1u) == (unsigned)(NB2 - 1));
    __syncthreads();
    if (!sLast) return;
    __threadfence();

    bool desperate = (ticket[1] != 0u);
    int m = 0;

    if (!desperate) {
        // prefix offsets (diagnostic only; regions read in-place below)
        if (t == 0) {
            unsigned acc = 0;
            #pragma unroll
            for (int r = 0; r < NB2; ++r) { soff[r] = acc; acc += counts[r]; }
            soff[NB2] = acc;
        }
        __syncthreads();
        const int S = (int)soff[NB2];   // ~4.3K survivors

        // hist the survivors (values still L2-hot)
        for (int i = t; i < NBUCK; i += 256) h[i] = 0;
        __syncthreads();
        for (int idx = t; idx < NB2 * BCAP; idx += 256) {
            const int r = idx / BCAP, j = idx % BCAP;
            if ((unsigned)j < counts[r])
                atomicAdd(&h[key_of(ws_v[r * BCAP + j]) >> KSHIFT], 1u);
        }
        __syncthreads();
        {
            const int hb = NBUCK - 16 * t;
            unsigned s = 0;
            for (int b = hb - 16; b < hb; ++b) s += h[b];
            csum[t] = s;
        }
        __syncthreads();
        if (t == 0) {
            const unsigned need = (unsigned)min(KSEL, S);
            unsigned cum = 0;
            int tc = 0;
            for (; tc < 256; ++tc) {
                if (cum + csum[tc] >= need) break;
                cum += csum[tc];
            }
            unsigned B2 = 0;
            if (tc < 256) {
                int b = NBUCK - 16 * tc - 1;
                for (int k = 0; k < 16; ++k, --b) {
                    cum += h[b];
                    if (cum >= need) { B2 = (unsigned)b; break; }
                }
            }
            sB = B2;
            sCnt = 0;
        }
        __syncthreads();
        const unsigned B2 = sB;

        // compact globally-thresholded survivors into LDS
        for (int idx = t; idx < NB2 * BCAP; idx += 256) {
            const int r = idx / BCAP, j = idx % BCAP;
            if ((unsigned)j < counts[r]) {
                const float v = ws_v[r * BCAP + j];
                if ((key_of(v) >> KSHIFT) >= B2) {
                    const unsigned p = atomicAdd(&sCnt, 1u);
                    if (p < FCAP) { sv[p] = v; si[p] = ws_i[r * BCAP + j]; }
                }
            }
        }
        __syncthreads();
        if (sCnt > FCAP) desperate = true;             // tie pathology
        m = (int)min(sCnt, (unsigned)FCAP);
        __syncthreads();
    }

    if (desperate) {
        // Ultra-safe path: KSEL sequential global argmaxes (never expected).
        __shared__ float sPv; __shared__ int sPi;
        if (t == 0) { sPv = INFINITY; sPi = -1; }
        __syncthreads();
        for (int k = 0; k < KSEL; ++k) {
            const float pv = sPv; const int pi = sPi;
            float bv = -INFINITY; int bi = INT_MAX;
            for (int i = t; i < n; i += 256) {
                const float v = scores[i];
                if (comes_first(pv, pi, v, i) && comes_first(v, i, bv, bi)) { bv = v; bi = i; }
            }
            #pragma unroll
            for (int off = 32; off > 0; off >>= 1) {
                const float ov = __shfl_xor(bv, off);
                const int   oi = __shfl_xor(bi, off);
                if (comes_first(ov, oi, bv, bi)) { bv = ov; bi = oi; }
            }
            const int w = t >> 6;
            if ((t & 63) == 0) { wv[w] = bv; wbi[w] = bi; }
            __syncthreads();
            if (t == 0) {
                float fv = wv[0]; int fi = wbi[0];
                #pragma unroll
                for (int j = 1; j < 4; ++j)
                    if (comes_first(wv[j], wbi[j], fv, fi)) { fv = wv[j]; fi = wbi[j]; }
                out[k] = (float)cand[fi];
                sPv = fv; sPi = fi;
            }
            __syncthreads();
        }
        return;
    }

    if (m <= 256) {
        // bitonic sort of 256 slots: value desc, index asc (lax.top_k order)
        if (t >= m) { sv[t] = -INFINITY; si[t] = INT_MAX; }
        __syncthreads();
        for (int k = 2; k <= 256; k <<= 1) {
            for (int j = k >> 1; j > 0; j >>= 1) {
                const int p = t ^ j;
                if (p > t) {
                    const float va = sv[t], vb = sv[p];
                    const int   ia = si[t], ib = si[p];
                    const bool asc = ((t & k) == 0);
                    const bool doSwap = asc ? comes_first(vb, ib, va, ia)
                                            : comes_first(va, ia, vb, ib);
                    if (doSwap) { sv[t] = vb; si[t] = ib; sv[p] = va; si[p] = ia; }
                }
                __syncthreads();
            }
        }
        if (t < KSEL) out[t] = (float)cand[si[t]];
        return;
    }

    // Serial argmax over m <= FCAP LDS survivors (never expected).
    for (int i = t + m; i < FCAP; i += 256) { sv[i] = -INFINITY; si[i] = INT_MAX; }
    __syncthreads();
    for (int k = 0; k < KSEL; ++k) {
        float bv = -INFINITY; int bi = INT_MAX; int bs = 0;
        for (int i = t; i < FCAP; i += 256) {
            if (comes_first(sv[i], si[i], bv, bi)) { bv = sv[i]; bi = si[i]; bs = i; }
        }
        int bsv = bs;
        #pragma unroll
        for (int off = 32; off > 0; off >>= 1) {
            const float ov = __shfl_xor(bv, off);
            const int   oi = __shfl_xor(bi, off);
            const int   os = __shfl_xor(bsv, off);
            if (comes_first(ov, oi, bv, bi)) { bv = ov; bi = oi; bsv = os; }
        }
        const int w = t >> 6;
        if ((t & 63) == 0) { wv[w] = bv; wbi[w] = bi; csum[w] = (unsigned)bsv; }
        __syncthreads();
        if (t == 0) {
            float fv = wv[0]; int fi = wbi[0]; int fs = (int)csum[0];
            #pragma unroll
            for (int j = 1; j < 4; ++j)
                if (comes_first(wv[j], wbi[j], fv, fi)) { fv = wv[j]; fi = wbi[j]; fs = (int)csum[j]; }
            out[k] = (float)cand[fi];
            sv[fs] = -INFINITY;
            si[fs] = INT_MAX;
        }
        __syncthreads();
    }
}

extern "C" void kernel_launch(void* const* d_in, const int* in_sizes, int n_in,
                              void* d_out, int out_size, void* d_ws, size_t ws_size,
                              hipStream_t stream) {
    const float* infl  = (const float*)d_in[0];   // [num_cand]
    const float* feats = (const float*)d_in[1];   // [num_nodes, 256]
    const int*   cand  = (const int*)d_in[2];     // [num_cand]
    const float* inj   = (const float*)d_in[3];   // [256]

    const int num_cand = in_sizes[0];

    float* out    = (float*)d_out;          // [0..64): indices-as-f32
    float* scores = (float*)d_out + KSEL;   // [64..64+num_cand): edge scores

    unsigned* ws_counts = (unsigned*)d_ws;                // NB2
    unsigned* ws_ticket = ws_counts + NB2;                // 2 (done, oflow)
    float*    ws_v      = (float*)(ws_ticket + 2);        // NB2*BCAP
    int*      ws_i      = (int*)(ws_v + NB2 * BCAP);      // NB2*BCAP

    // 1. Edge scores: one-shot waves, CPW=8 (zeroes the 2 ticket words).
    {
        const int waves  = (num_cand + CPW - 1) / CPW;
        const int blocks = (waves + 3) / 4;
        edge_score_kernel<<<blocks, 256, 0, stream>>>(
            infl, feats, cand, inj, scores, ws_ticket, num_cand);
    }

    // 2. Full selection: local-threshold compaction + last-block top-64.
    select_kernel<<<NB2, 256, 0, stream>>>(
        scores, ws_counts, ws_ticket, ws_v, ws_i, cand, out, num_cand);
}